// Round 7
// baseline (2375.075 us; speedup 1.0000x reference)
//
#include <hip/hip_runtime.h>
#include <math.h>

#define DC 256
#define NBINS 1024
#define NQ 8
#define NTOK 32768      // B*T
#define D_IN 512
#define DCH 32          // k-chunk (depth) for all GEMMs
#define TOK_PER_BLK 64  // tokens per rvq block (64 -> 512 blocks = 2 blocks/CU)
#define BCH 256         // bin chunk in rvq
#define RVQ_THREADS 512
#define RVQ_BLOCKS (NTOK / TOK_PER_BLK)

// ---- numpy pairwise_sum bit-emulation (loops.c.src: 8 accumulators, 128-block) ----
__device__ __forceinline__ float np_sumsq128(const float* a) {
#pragma clang fp contract(off)
  float r0 = a[0] * a[0], r1 = a[1] * a[1], r2 = a[2] * a[2], r3 = a[3] * a[3];
  float r4 = a[4] * a[4], r5 = a[5] * a[5], r6 = a[6] * a[6], r7 = a[7] * a[7];
  for (int i = 8; i < 128; i += 8) {
    r0 += a[i + 0] * a[i + 0]; r1 += a[i + 1] * a[i + 1];
    r2 += a[i + 2] * a[i + 2]; r3 += a[i + 3] * a[i + 3];
    r4 += a[i + 4] * a[i + 4]; r5 += a[i + 5] * a[i + 5];
    r6 += a[i + 6] * a[i + 6]; r7 += a[i + 7] * a[i + 7];
  }
  return ((r0 + r1) + (r2 + r3)) + ((r4 + r5) + (r6 + r7));
}

// np.sum(x*x, -1) over 256: pairwise split 128+128, fl(lo+hi)
__device__ __forceinline__ float np_sumsq256(const float* a) {
#pragma clang fp contract(off)
  float lo = np_sumsq128(a);
  float hi = np_sumsq128(a + 128);
  return lo + hi;
}

// ---------------- K0: codebook squared norms, np-pairwise bits ----------------
__global__ void e2_np_kernel(const float* __restrict__ cb, float* __restrict__ e2) {
  int b = blockIdx.x * 256 + threadIdx.x;  // 0..8191
  e2[b] = np_sumsq256(cb + (size_t)b * DC);
}

// ---------------- K1: in-projection, OpenBLAS-sgemm bit-emulation ----------------
// C[m][n] = fl(s1 + s2): s1 = seqFMA_{k<384}, s2 = seqFMA_{384<=k<512} (kc=384),
// h = tanhf(fl(C + b)).
__global__ __launch_bounds__(256) void in_proj_kernel(
    const float* __restrict__ x, const float* __restrict__ in_w,
    const float* __restrict__ in_b, float* __restrict__ res) {
  __shared__ __align__(16) float aT[DCH][68];
  __shared__ __align__(16) float bT[DCH][68];
  const int thr = threadIdx.x;
  const int tx = thr & 15, ty = thr >> 4;
  const int m0 = blockIdx.x * 64, n0 = blockIdx.y * 64;
  float acc[4][4] = {};
  float s1[4][4] = {};
  for (int kc = 0; kc < D_IN; kc += DCH) {
    if (kc == 384) {  // OpenBLAS kc-split
#pragma unroll
      for (int i = 0; i < 4; ++i)
#pragma unroll
        for (int j = 0; j < 4; ++j) { s1[i][j] = acc[i][j]; acc[i][j] = 0.f; }
    }
    __syncthreads();
#pragma unroll
    for (int i = 0; i < 2; ++i) {
      int q = thr + 256 * i;
      int m = q >> 3, kk = (q & 7) << 2;
      float4 v = *reinterpret_cast<const float4*>(x + (size_t)(m0 + m) * D_IN + kc + kk);
      aT[kk + 0][m] = v.x; aT[kk + 1][m] = v.y; aT[kk + 2][m] = v.z; aT[kk + 3][m] = v.w;
      float4 w = *reinterpret_cast<const float4*>(in_w + (size_t)(n0 + m) * D_IN + kc + kk);
      bT[kk + 0][m] = w.x; bT[kk + 1][m] = w.y; bT[kk + 2][m] = w.z; bT[kk + 3][m] = w.w;
    }
    __syncthreads();
#pragma unroll 8
    for (int d = 0; d < DCH; ++d) {  // k ascending: one fused-FMA chain per output
      float4 a = *reinterpret_cast<const float4*>(&aT[d][ty * 4]);
      float4 b = *reinterpret_cast<const float4*>(&bT[d][tx * 4]);
      float av[4] = {a.x, a.y, a.z, a.w};
      float bv[4] = {b.x, b.y, b.z, b.w};
#pragma unroll
      for (int i = 0; i < 4; ++i)
#pragma unroll
        for (int j = 0; j < 4; ++j) acc[i][j] = fmaf(av[i], bv[j], acc[i][j]);
    }
  }
#pragma unroll
  for (int i = 0; i < 4; ++i) {
    int m = m0 + ty * 4 + i, n = n0 + tx * 4;
    float4 hv;
#pragma unroll
    for (int j = 0; j < 4; ++j) {
#pragma clang fp contract(off)
      float c = s1[i][j] + acc[i][j];
      float pre = c + in_b[n + j];
      ((float*)&hv)[j] = tanhf(pre);
    }
    *reinterpret_cast<float4*>(res + (size_t)m * DC + n) = hv;
  }
}

// ---------------- K2: fused 8-stage RVQ, np-bit dist for ALL rows ----------------
// ein via fused-FMA chain over d ascending (== OpenBLAS sgemm microkernel bits);
// dist assembled np-style: fl(fl(r2 - fl(2*ein)) + e2), r2/e2 np-pairwise bits;
// argmin strict-< ascending (np first-min); state update fl(r - e).
// 64 tokens/block -> 512 blocks -> 2 blocks/CU to overlap barrier stalls.
__global__ __launch_bounds__(RVQ_THREADS, 4) void rvq_kernel(
    const float* __restrict__ cb, const float* __restrict__ e2,
    float* __restrict__ res, float* __restrict__ idx_f,
    double* __restrict__ partial) {
  __shared__ __align__(16) float rT[DCH][TOK_PER_BLK + 4];  // [d][token] 8.7 KB
  __shared__ __align__(16) float eT[DCH][BCH + 4];          // [d][bin]  33.3 KB
  __shared__ float half_l[TOK_PER_BLK][2];
  __shared__ float r2_l[TOK_PER_BLK];
  __shared__ int win_l[TOK_PER_BLK];
  __shared__ double wsum[8];
  const int thr = threadIdx.x;
  const int tx = thr & 31;   // bins: {tx*4..+3} U {128+tx*4..+3}
  const int ty = thr >> 5;   // 0..15 -> rows ty*4..ty*4+3
  const int m0 = blockIdx.x * TOK_PER_BLK;
  double sqacc = 0.0;

  for (int s = 0; s < NQ; ++s) {
    const float* cbs = cb + (size_t)s * NBINS * DC;
    const float* e2s = e2 + s * NBINS;

    // --- np-bit r2 for the block's 64 rows (current residual state) ---
    if (thr < 128) {
      int row = thr >> 1, hf = thr & 1;
      half_l[row][hf] = np_sumsq128(res + (size_t)(m0 + row) * DC + hf * 128);
    }
    __syncthreads();
    if (thr < TOK_PER_BLK) {
#pragma clang fp contract(off)
      r2_l[thr] = half_l[thr][0] + half_l[thr][1];
    }
    __syncthreads();
    float r2v[4];
#pragma unroll
    for (int i = 0; i < 4; ++i) r2v[i] = r2_l[ty * 4 + i];

    float min1[4]; int idx1[4];
#pragma unroll
    for (int i = 0; i < 4; ++i) { min1[i] = 3.4028235e38f; idx1[i] = 0; }

    for (int bc = 0; bc < NBINS; bc += BCH) {
      float acc[4][8] = {};
      for (int dc = 0; dc < DC; dc += DCH) {
        __syncthreads();
        // stage residual tile: 64 tok x 32 d (transposed), 1 float4/thread
        {
          int m = thr >> 3, kk = (thr & 7) << 2;
          float4 v = *reinterpret_cast<const float4*>(res + (size_t)(m0 + m) * DC + dc + kk);
          rT[kk + 0][m] = v.x; rT[kk + 1][m] = v.y; rT[kk + 2][m] = v.z; rT[kk + 3][m] = v.w;
        }
        // stage codebook tile: 256 bins x 32 d (transposed), 4 float4/thread
#pragma unroll
        for (int i = 0; i < 4; ++i) {
          int q = thr + RVQ_THREADS * i;
          int b = q >> 3, kk = (q & 7) << 2;
          float4 v = *reinterpret_cast<const float4*>(cbs + (size_t)(bc + b) * DC + dc + kk);
          eT[kk + 0][b] = v.x; eT[kk + 1][b] = v.y; eT[kk + 2][b] = v.z; eT[kk + 3][b] = v.w;
        }
        __syncthreads();
#pragma unroll 4
        for (int d = 0; d < DCH; ++d) {  // d ascending -> sgemm-chain bits
          float4 A0 = *reinterpret_cast<const float4*>(&rT[d][ty * 4]);
          float4 B0 = *reinterpret_cast<const float4*>(&eT[d][tx * 4]);
          float4 B1 = *reinterpret_cast<const float4*>(&eT[d][128 + tx * 4]);
          float av[4] = {A0.x, A0.y, A0.z, A0.w};
          float bv[8] = {B0.x, B0.y, B0.z, B0.w, B1.x, B1.y, B1.z, B1.w};
#pragma unroll
          for (int i = 0; i < 4; ++i)
#pragma unroll
            for (int j = 0; j < 8; ++j) acc[i][j] = fmaf(av[i], bv[j], acc[i][j]);
        }
      }
      // np-bit dist assembly + running first-min (ascending bin order)
      {
#pragma clang fp contract(off)
#pragma unroll
        for (int j = 0; j < 8; ++j) {
          int bl = (j < 4) ? (tx * 4 + j) : (128 + tx * 4 + (j - 4));
          int b = bc + bl;
          float ee = e2s[b];
#pragma unroll
          for (int i = 0; i < 4; ++i) {
            float t = r2v[i] - 2.0f * acc[i][j];  // fl(r2 - fl(2*ein))
            float dist = t + ee;                  // fl(. + e2)
            if (dist < min1[i]) { min1[i] = dist; idx1[i] = b; }
          }
        }
      }
    }
    // lexicographic first-min merge across the 32 lanes sharing each row
#pragma unroll
    for (int i = 0; i < 4; ++i) {
      float m1 = min1[i]; int i1 = idx1[i];
#pragma unroll
      for (int m = 16; m >= 1; m >>= 1) {
        float om1 = __shfl_xor(m1, m, 64);
        int   oi1 = __shfl_xor(i1, m, 64);
        if (om1 < m1 || (om1 == m1 && oi1 < i1)) { m1 = om1; i1 = oi1; }
      }
      if (tx == 0) win_l[ty * 4 + i] = i1;
    }
    __syncthreads();
    // fp32 residual update (single-rounded sub = np state bits) + fp64 commit acc
    {
      int row = thr >> 3;            // 8 threads per row
      int dbase = (thr & 7) << 5;    // 32 d each
      int wbin = win_l[row];
      const float* erow = cbs + (size_t)wbin * DC;
      float* rrow = res + (size_t)(m0 + row) * DC;
#pragma unroll
      for (int t = 0; t < 8; ++t) {
        int d = dbase + t * 4;
        float4 rv = *reinterpret_cast<const float4*>(rrow + d);
        float4 ev = *reinterpret_cast<const float4*>(erow + d);
        rv.x -= ev.x; rv.y -= ev.y; rv.z -= ev.z; rv.w -= ev.w;
        sqacc += (double)rv.x * rv.x + (double)rv.y * rv.y
               + (double)rv.z * rv.z + (double)rv.w * rv.w;
        *reinterpret_cast<float4*>(rrow + d) = rv;
      }
      if (thr < TOK_PER_BLK) idx_f[(size_t)s * NTOK + m0 + thr] = (float)win_l[thr];
    }
    __syncthreads();
  }
  // deterministic per-block commit partial (fp64)
#pragma unroll
  for (int m = 1; m < 64; m <<= 1) sqacc += __shfl_xor(sqacc, m, 64);
  if ((thr & 63) == 0) wsum[thr >> 6] = sqacc;
  __syncthreads();
  if (thr == 0) {
    double t = 0.0;
#pragma unroll
    for (int w = 0; w < 8; ++w) t += wsum[w];
    partial[blockIdx.x] = t;
  }
}

// ---------------- K4: finalize commit loss ----------------
__global__ void finalize_kernel(const double* __restrict__ partial, float* __restrict__ out_last) {
  if (threadIdx.x == 0 && blockIdx.x == 0) {
    double t = 0.0;
    for (int i = 0; i < RVQ_BLOCKS; ++i) t += partial[i];
    out_last[0] = (float)(0.1 * t / 8388608.0);
  }
}

// ---------------- K3: out-projection GEMM from gathered quantized ----------------
__global__ __launch_bounds__(256) void out_proj_kernel(
    const float* __restrict__ cb, const float* __restrict__ idx_f,
    const float* __restrict__ out_w, const float* __restrict__ out_b,
    float* __restrict__ out) {
  __shared__ __align__(16) float aT[DCH][68];
  __shared__ __align__(16) float bT[DCH][68];
  __shared__ int idx_l[NQ][64];
  const int thr = threadIdx.x;
  const int tx = thr & 15, ty = thr >> 4;
  const int m0 = blockIdx.x * 64, n0 = blockIdx.y * 64;
#pragma unroll
  for (int i = 0; i < 2; ++i) {
    int q = thr + 256 * i;
    int s = q >> 6, m = q & 63;
    idx_l[s][m] = (int)idx_f[(size_t)s * NTOK + m0 + m];
  }
  float acc[4][4] = {};
  for (int kc = 0; kc < DC; kc += DCH) {
    __syncthreads();
#pragma unroll
    for (int i = 0; i < 2; ++i) {
      int q = thr + 256 * i;
      int m = q >> 3, kk = (q & 7) << 2;
      float4 v = {0.f, 0.f, 0.f, 0.f};
#pragma unroll
      for (int s = 0; s < NQ; ++s) {
        const float4 e = *reinterpret_cast<const float4*>(
            cb + ((size_t)s * NBINS + idx_l[s][m]) * DC + kc + kk);
        v.x += e.x; v.y += e.y; v.z += e.z; v.w += e.w;
      }
      aT[kk + 0][m] = v.x; aT[kk + 1][m] = v.y; aT[kk + 2][m] = v.z; aT[kk + 3][m] = v.w;
      float4 w = *reinterpret_cast<const float4*>(out_w + (size_t)(n0 + m) * DC + kc + kk);
      bT[kk + 0][m] = w.x; bT[kk + 1][m] = w.y; bT[kk + 2][m] = w.z; bT[kk + 3][m] = w.w;
    }
    __syncthreads();
#pragma unroll 8
    for (int d = 0; d < DCH; ++d) {
      float4 a = *reinterpret_cast<const float4*>(&aT[d][ty * 4]);
      float4 b = *reinterpret_cast<const float4*>(&bT[d][tx * 4]);
      float av[4] = {a.x, a.y, a.z, a.w};
      float bv[4] = {b.x, b.y, b.z, b.w};
#pragma unroll
      for (int i = 0; i < 4; ++i)
#pragma unroll
        for (int j = 0; j < 4; ++j) acc[i][j] = fmaf(av[i], bv[j], acc[i][j]);
    }
  }
#pragma unroll
  for (int i = 0; i < 4; ++i) {
    int m = m0 + ty * 4 + i, n = n0 + tx * 4;
    float4 o;
    o.x = acc[i][0] + out_b[n + 0];
    o.y = acc[i][1] + out_b[n + 1];
    o.z = acc[i][2] + out_b[n + 2];
    o.w = acc[i][3] + out_b[n + 3];
    *reinterpret_cast<float4*>(out + (size_t)m * D_IN + n) = o;
  }
}

extern "C" void kernel_launch(void* const* d_in, const int* in_sizes, int n_in,
                              void* d_out, int out_size, void* d_ws, size_t ws_size,
                              hipStream_t stream) {
  (void)in_sizes; (void)n_in; (void)out_size; (void)d_ws; (void)ws_size;
  const float* x     = (const float*)d_in[0];
  const float* in_w  = (const float*)d_in[1];
  const float* in_b  = (const float*)d_in[2];
  const float* out_w = (const float*)d_in[3];
  const float* out_b = (const float*)d_in[4];
  const float* cb    = (const float*)d_in[5];
  float* out = (float*)d_out;
  // d_out layout: [0,16777216) final out (scratch until K3), [16777216,17039360)
  // idxs (float), [17039360] commit loss. Scratch packed in the out region,
  // consumed before K3 overwrites it:
  float* res    = out;                          // 8,388,608 f32 residual (np fp32 state)
  float* e2     = out + 8388608;                // 8192 f32 (np-pairwise bits)
  double* part  = (double*)(out + 8404992);     // 512 f64
  float* idx_f  = out + 16777216;               // 262,144 f32
  float* c_out  = out + 17039360;               // 1 f32

  hipLaunchKernelGGL(e2_np_kernel, dim3(32), dim3(256), 0, stream, cb, e2);
  hipLaunchKernelGGL(in_proj_kernel, dim3(512, 4), dim3(256), 0, stream, x, in_w, in_b, res);
  hipLaunchKernelGGL(rvq_kernel, dim3(RVQ_BLOCKS), dim3(RVQ_THREADS), 0, stream, cb, e2, res, idx_f, part);
  hipLaunchKernelGGL(finalize_kernel, dim3(1), dim3(64), 0, stream, part, c_out);
  hipLaunchKernelGGL(out_proj_kernel, dim3(512, 8), dim3(256), 0, stream, cb, idx_f, out_w, out_b, out);
}

// Round 8
// 2294.982 us; speedup vs baseline: 1.0349x; 1.0349x over previous
//
#include <hip/hip_runtime.h>
#include <math.h>

#define DC 256
#define NBINS 1024
#define NQ 8
#define NTOK 32768      // B*T
#define D_IN 512
#define DCH 32          // k-chunk (depth) for all GEMMs
#define TOK_PER_BLK 64  // tokens per rvq block -> 512 blocks, 2 blocks/CU
#define BCH 512         // bin chunk in rvq (4 quarters of 128)
#define RVQ_THREADS 256
#define RVQ_BLOCKS (NTOK / TOK_PER_BLK)

// ---- numpy pairwise_sum bit-emulation (loops.c.src: 8 accumulators, 128-block) ----
__device__ __forceinline__ float np_sumsq128(const float* a) {
#pragma clang fp contract(off)
  float r0 = a[0] * a[0], r1 = a[1] * a[1], r2 = a[2] * a[2], r3 = a[3] * a[3];
  float r4 = a[4] * a[4], r5 = a[5] * a[5], r6 = a[6] * a[6], r7 = a[7] * a[7];
  for (int i = 8; i < 128; i += 8) {
    r0 += a[i + 0] * a[i + 0]; r1 += a[i + 1] * a[i + 1];
    r2 += a[i + 2] * a[i + 2]; r3 += a[i + 3] * a[i + 3];
    r4 += a[i + 4] * a[i + 4]; r5 += a[i + 5] * a[i + 5];
    r6 += a[i + 6] * a[i + 6]; r7 += a[i + 7] * a[i + 7];
  }
  return ((r0 + r1) + (r2 + r3)) + ((r4 + r5) + (r6 + r7));
}

// np.sum(x*x, -1) over 256: pairwise split 128+128, fl(lo+hi)
__device__ __forceinline__ float np_sumsq256(const float* a) {
#pragma clang fp contract(off)
  float lo = np_sumsq128(a);
  float hi = np_sumsq128(a + 128);
  return lo + hi;
}

// ---------------- K0: codebook squared norms, np-pairwise bits ----------------
__global__ void e2_np_kernel(const float* __restrict__ cb, float* __restrict__ e2) {
  int b = blockIdx.x * 256 + threadIdx.x;  // 0..8191
  e2[b] = np_sumsq256(cb + (size_t)b * DC);
}

// ---------------- K1: in-projection, OpenBLAS-sgemm bit-emulation ----------------
// C[m][n] = fl(s1 + s2): s1 = seqFMA_{k<384}, s2 = seqFMA_{384<=k<512} (kc=384),
// h = tanhf(fl(C + b)).
__global__ __launch_bounds__(256) void in_proj_kernel(
    const float* __restrict__ x, const float* __restrict__ in_w,
    const float* __restrict__ in_b, float* __restrict__ res) {
  __shared__ __align__(16) float aT[DCH][68];
  __shared__ __align__(16) float bT[DCH][68];
  const int thr = threadIdx.x;
  const int tx = thr & 15, ty = thr >> 4;
  const int m0 = blockIdx.x * 64, n0 = blockIdx.y * 64;
  float acc[4][4] = {};
  float s1[4][4] = {};
  for (int kc = 0; kc < D_IN; kc += DCH) {
    if (kc == 384) {  // OpenBLAS kc-split
#pragma unroll
      for (int i = 0; i < 4; ++i)
#pragma unroll
        for (int j = 0; j < 4; ++j) { s1[i][j] = acc[i][j]; acc[i][j] = 0.f; }
    }
    __syncthreads();
#pragma unroll
    for (int i = 0; i < 2; ++i) {
      int q = thr + 256 * i;
      int m = q >> 3, kk = (q & 7) << 2;
      float4 v = *reinterpret_cast<const float4*>(x + (size_t)(m0 + m) * D_IN + kc + kk);
      aT[kk + 0][m] = v.x; aT[kk + 1][m] = v.y; aT[kk + 2][m] = v.z; aT[kk + 3][m] = v.w;
      float4 w = *reinterpret_cast<const float4*>(in_w + (size_t)(n0 + m) * D_IN + kc + kk);
      bT[kk + 0][m] = w.x; bT[kk + 1][m] = w.y; bT[kk + 2][m] = w.z; bT[kk + 3][m] = w.w;
    }
    __syncthreads();
#pragma unroll 8
    for (int d = 0; d < DCH; ++d) {  // k ascending: one fused-FMA chain per output
      float4 a = *reinterpret_cast<const float4*>(&aT[d][ty * 4]);
      float4 b = *reinterpret_cast<const float4*>(&bT[d][tx * 4]);
      float av[4] = {a.x, a.y, a.z, a.w};
      float bv[4] = {b.x, b.y, b.z, b.w};
#pragma unroll
      for (int i = 0; i < 4; ++i)
#pragma unroll
        for (int j = 0; j < 4; ++j) acc[i][j] = fmaf(av[i], bv[j], acc[i][j]);
    }
  }
#pragma unroll
  for (int i = 0; i < 4; ++i) {
    int m = m0 + ty * 4 + i, n = n0 + tx * 4;
    float4 hv;
#pragma unroll
    for (int j = 0; j < 4; ++j) {
#pragma clang fp contract(off)
      float c = s1[i][j] + acc[i][j];
      float pre = c + in_b[n + j];
      ((float*)&hv)[j] = tanhf(pre);
    }
    *reinterpret_cast<float4*>(res + (size_t)m * DC + n) = hv;
  }
}

// ---------------- K2: fused 8-stage RVQ, np-bit dist for ALL rows ----------------
// ein via fused-FMA chain over d ascending (== OpenBLAS sgemm microkernel bits);
// dist assembled np-style: fl(fl(r2 - fl(2*ein)) + e2), r2/e2 np-pairwise bits;
// argmin strict-< ascending (np first-min); state update fl(r - e).
// 8 rows x 16 bins per thread: 6 ds_read_b128 per 128 FMA (0.75 B/FMA).
__global__ __launch_bounds__(RVQ_THREADS, 2) void rvq_kernel(
    const float* __restrict__ cb, const float* __restrict__ e2,
    float* __restrict__ res, float* __restrict__ idx_f,
    double* __restrict__ partial) {
  __shared__ __align__(16) float rT[DCH][TOK_PER_BLK + 4];  // [d][token]  8.7 KB
  __shared__ __align__(16) float eT[DCH][BCH + 4];          // [d][bin]   66.0 KB
  __shared__ float half_l[TOK_PER_BLK][2];
  __shared__ float r2_l[TOK_PER_BLK];
  __shared__ int win_l[TOK_PER_BLK];
  __shared__ double wsum[4];
  const int thr = threadIdx.x;
  const int tx = thr & 31;   // bin quarters: q*128 + tx*4 + (0..3), q=0..3
  const int ty = thr >> 5;   // 0..7 -> rows ty*8..ty*8+7
  const int m0 = blockIdx.x * TOK_PER_BLK;
  double sqacc = 0.0;

  for (int s = 0; s < NQ; ++s) {
    const float* cbs = cb + (size_t)s * NBINS * DC;
    const float* e2s = e2 + s * NBINS;

    // --- np-bit r2 for the block's 64 rows (current residual state) ---
    if (thr < 128) {
      int row = thr >> 1, hf = thr & 1;
      half_l[row][hf] = np_sumsq128(res + (size_t)(m0 + row) * DC + hf * 128);
    }
    __syncthreads();
    if (thr < TOK_PER_BLK) {
#pragma clang fp contract(off)
      r2_l[thr] = half_l[thr][0] + half_l[thr][1];
    }
    __syncthreads();
    float r2v[8];
#pragma unroll
    for (int i = 0; i < 8; ++i) r2v[i] = r2_l[ty * 8 + i];

    float min1[8]; int idx1[8];
#pragma unroll
    for (int i = 0; i < 8; ++i) { min1[i] = 3.4028235e38f; idx1[i] = 0; }

    for (int bc = 0; bc < NBINS; bc += BCH) {
      float acc[8][16] = {};
      for (int dc = 0; dc < DC; dc += DCH) {
        __syncthreads();
        // stage residual tile: 64 tok x 32 d (transposed), 2 float4/thread
#pragma unroll
        for (int i = 0; i < 2; ++i) {
          int q = thr + RVQ_THREADS * i;
          int m = q >> 3, kk = (q & 7) << 2;
          float4 v = *reinterpret_cast<const float4*>(res + (size_t)(m0 + m) * DC + dc + kk);
          rT[kk + 0][m] = v.x; rT[kk + 1][m] = v.y; rT[kk + 2][m] = v.z; rT[kk + 3][m] = v.w;
        }
        // stage codebook tile: 512 bins x 32 d (transposed), 16 float4/thread
#pragma unroll 4
        for (int i = 0; i < 16; ++i) {
          int q = thr + RVQ_THREADS * i;
          int b = q >> 3, kk = (q & 7) << 2;
          float4 v = *reinterpret_cast<const float4*>(cbs + (size_t)(bc + b) * DC + dc + kk);
          eT[kk + 0][b] = v.x; eT[kk + 1][b] = v.y; eT[kk + 2][b] = v.z; eT[kk + 3][b] = v.w;
        }
        __syncthreads();
#pragma unroll 2
        for (int d = 0; d < DCH; ++d) {  // d ascending -> sgemm-chain bits
          float4 A0 = *reinterpret_cast<const float4*>(&rT[d][ty * 8]);
          float4 A1 = *reinterpret_cast<const float4*>(&rT[d][ty * 8 + 4]);
          float4 B0 = *reinterpret_cast<const float4*>(&eT[d][tx * 4]);
          float4 B1 = *reinterpret_cast<const float4*>(&eT[d][128 + tx * 4]);
          float4 B2 = *reinterpret_cast<const float4*>(&eT[d][256 + tx * 4]);
          float4 B3 = *reinterpret_cast<const float4*>(&eT[d][384 + tx * 4]);
          float av[8] = {A0.x, A0.y, A0.z, A0.w, A1.x, A1.y, A1.z, A1.w};
          float bv[16] = {B0.x, B0.y, B0.z, B0.w, B1.x, B1.y, B1.z, B1.w,
                          B2.x, B2.y, B2.z, B2.w, B3.x, B3.y, B3.z, B3.w};
#pragma unroll
          for (int i = 0; i < 8; ++i)
#pragma unroll
            for (int j = 0; j < 16; ++j) acc[i][j] = fmaf(av[i], bv[j], acc[i][j]);
        }
      }
      // np-bit dist assembly + running first-min (ascending bin order per lane)
      {
#pragma clang fp contract(off)
#pragma unroll
        for (int j = 0; j < 16; ++j) {
          int b = bc + (j >> 2) * 128 + tx * 4 + (j & 3);
          float ee = e2s[b];
#pragma unroll
          for (int i = 0; i < 8; ++i) {
            float t = r2v[i] - 2.0f * acc[i][j];  // fl(r2 - fl(2*ein))
            float dist = t + ee;                  // fl(. + e2)
            if (dist < min1[i]) { min1[i] = dist; idx1[i] = b; }
          }
        }
      }
    }
    // lexicographic first-min merge across the 32 lanes sharing each row-group
#pragma unroll
    for (int i = 0; i < 8; ++i) {
      float m1 = min1[i]; int i1 = idx1[i];
#pragma unroll
      for (int m = 16; m >= 1; m >>= 1) {
        float om1 = __shfl_xor(m1, m, 64);
        int   oi1 = __shfl_xor(i1, m, 64);
        if (om1 < m1 || (om1 == m1 && oi1 < i1)) { m1 = om1; i1 = oi1; }
      }
      if (tx == 0) win_l[ty * 8 + i] = i1;
    }
    __syncthreads();
    // fp32 residual update (single-rounded sub = np state bits) + fp64 commit acc
    {
      int row = thr >> 2;            // 4 threads per row
      int dbase = (thr & 3) << 6;    // 64 d each
      int wbin = win_l[row];
      const float* erow = cbs + (size_t)wbin * DC;
      float* rrow = res + (size_t)(m0 + row) * DC;
#pragma unroll
      for (int t = 0; t < 16; ++t) {
        int d = dbase + t * 4;
        float4 rv = *reinterpret_cast<const float4*>(rrow + d);
        float4 ev = *reinterpret_cast<const float4*>(erow + d);
        rv.x -= ev.x; rv.y -= ev.y; rv.z -= ev.z; rv.w -= ev.w;
        sqacc += (double)rv.x * rv.x + (double)rv.y * rv.y
               + (double)rv.z * rv.z + (double)rv.w * rv.w;
        *reinterpret_cast<float4*>(rrow + d) = rv;
      }
      if (thr < TOK_PER_BLK) idx_f[(size_t)s * NTOK + m0 + thr] = (float)win_l[thr];
    }
    __syncthreads();
  }
  // deterministic per-block commit partial (fp64)
#pragma unroll
  for (int m = 1; m < 64; m <<= 1) sqacc += __shfl_xor(sqacc, m, 64);
  if ((thr & 63) == 0) wsum[thr >> 6] = sqacc;
  __syncthreads();
  if (thr == 0) {
    double t = 0.0;
#pragma unroll
    for (int w = 0; w < 4; ++w) t += wsum[w];
    partial[blockIdx.x] = t;
  }
}

// ---------------- K4: finalize commit loss ----------------
__global__ void finalize_kernel(const double* __restrict__ partial, float* __restrict__ out_last) {
  if (threadIdx.x == 0 && blockIdx.x == 0) {
    double t = 0.0;
    for (int i = 0; i < RVQ_BLOCKS; ++i) t += partial[i];
    out_last[0] = (float)(0.1 * t / 8388608.0);
  }
}

// ---------------- K3: out-projection GEMM from gathered quantized ----------------
__global__ __launch_bounds__(256) void out_proj_kernel(
    const float* __restrict__ cb, const float* __restrict__ idx_f,
    const float* __restrict__ out_w, const float* __restrict__ out_b,
    float* __restrict__ out) {
  __shared__ __align__(16) float aT[DCH][68];
  __shared__ __align__(16) float bT[DCH][68];
  __shared__ int idx_l[NQ][64];
  const int thr = threadIdx.x;
  const int tx = thr & 15, ty = thr >> 4;
  const int m0 = blockIdx.x * 64, n0 = blockIdx.y * 64;
#pragma unroll
  for (int i = 0; i < 2; ++i) {
    int q = thr + 256 * i;
    int s = q >> 6, m = q & 63;
    idx_l[s][m] = (int)idx_f[(size_t)s * NTOK + m0 + m];
  }
  float acc[4][4] = {};
  for (int kc = 0; kc < DC; kc += DCH) {
    __syncthreads();
#pragma unroll
    for (int i = 0; i < 2; ++i) {
      int q = thr + 256 * i;
      int m = q >> 3, kk = (q & 7) << 2;
      float4 v = {0.f, 0.f, 0.f, 0.f};
#pragma unroll
      for (int s = 0; s < NQ; ++s) {
        const float4 e = *reinterpret_cast<const float4*>(
            cb + ((size_t)s * NBINS + idx_l[s][m]) * DC + kc + kk);
        v.x += e.x; v.y += e.y; v.z += e.z; v.w += e.w;
      }
      aT[kk + 0][m] = v.x; aT[kk + 1][m] = v.y; aT[kk + 2][m] = v.z; aT[kk + 3][m] = v.w;
      float4 w = *reinterpret_cast<const float4*>(out_w + (size_t)(n0 + m) * DC + kc + kk);
      bT[kk + 0][m] = w.x; bT[kk + 1][m] = w.y; bT[kk + 2][m] = w.z; bT[kk + 3][m] = w.w;
    }
    __syncthreads();
#pragma unroll 8
    for (int d = 0; d < DCH; ++d) {
      float4 a = *reinterpret_cast<const float4*>(&aT[d][ty * 4]);
      float4 b = *reinterpret_cast<const float4*>(&bT[d][tx * 4]);
      float av[4] = {a.x, a.y, a.z, a.w};
      float bv[4] = {b.x, b.y, b.z, b.w};
#pragma unroll
      for (int i = 0; i < 4; ++i)
#pragma unroll
        for (int j = 0; j < 4; ++j) acc[i][j] = fmaf(av[i], bv[j], acc[i][j]);
    }
  }
#pragma unroll
  for (int i = 0; i < 4; ++i) {
    int m = m0 + ty * 4 + i, n = n0 + tx * 4;
    float4 o;
    o.x = acc[i][0] + out_b[n + 0];
    o.y = acc[i][1] + out_b[n + 1];
    o.z = acc[i][2] + out_b[n + 2];
    o.w = acc[i][3] + out_b[n + 3];
    *reinterpret_cast<float4*>(out + (size_t)m * D_IN + n) = o;
  }
}

extern "C" void kernel_launch(void* const* d_in, const int* in_sizes, int n_in,
                              void* d_out, int out_size, void* d_ws, size_t ws_size,
                              hipStream_t stream) {
  (void)in_sizes; (void)n_in; (void)out_size; (void)d_ws; (void)ws_size;
  const float* x     = (const float*)d_in[0];
  const float* in_w  = (const float*)d_in[1];
  const float* in_b  = (const float*)d_in[2];
  const float* out_w = (const float*)d_in[3];
  const float* out_b = (const float*)d_in[4];
  const float* cb    = (const float*)d_in[5];
  float* out = (float*)d_out;
  // d_out layout: [0,16777216) final out (scratch until K3), [16777216,17039360)
  // idxs (float), [17039360] commit loss. Scratch packed in the out region,
  // consumed before K3 overwrites it:
  float* res    = out;                          // 8,388,608 f32 residual (np fp32 state)
  float* e2     = out + 8388608;                // 8192 f32 (np-pairwise bits)
  double* part  = (double*)(out + 8404992);     // 512 f64
  float* idx_f  = out + 16777216;               // 262,144 f32
  float* c_out  = out + 17039360;               // 1 f32

  hipLaunchKernelGGL(e2_np_kernel, dim3(32), dim3(256), 0, stream, cb, e2);
  hipLaunchKernelGGL(in_proj_kernel, dim3(512, 4), dim3(256), 0, stream, x, in_w, in_b, res);
  hipLaunchKernelGGL(rvq_kernel, dim3(RVQ_BLOCKS), dim3(RVQ_THREADS), 0, stream, cb, e2, res, idx_f, part);
  hipLaunchKernelGGL(finalize_kernel, dim3(1), dim3(64), 0, stream, part, c_out);
  hipLaunchKernelGGL(out_proj_kernel, dim3(512, 8), dim3(256), 0, stream, cb, idx_f, out_w, out_b, out);
}